// Round 8
// baseline (424.843 us; speedup 1.0000x reference)
//
#include <hip/hip_runtime.h>
#include <cstdint>

// ---------------------------------------------------------------------------
// JanusCrossAttention: B=2,S=2048, Q_DIM=KV_DIM=2048, H=16, D=128, KVH=4
// I/O fp32; internals bf16 MFMA, fp32 accumulate.
//   1. cvt q_stream -> bf16 sb ; transpose weights -> bf16 [N][K]
//   2. xq = sb @ wqT  (m97-style global_load_lds GEMM)
//   3. cvt kv_stream -> sb ; xkv = sb @ wkvT  (fused K|V, N=1024)
//   4. per-head RMSNorm xq, xk
//   5. repack K and V^T into MFMA-fragment-major tiles
//   6. flash attention: 512-thread blocks, 8 waves = 2 q-halves x 4 key-
//      quarters (4-way split-K), 2 Q-fragments per wave (32 q-rows).
//      Combines R6's occupancy (16 waves/CU) with R7's operand reuse (each
//      K/V LDS read feeds 2 MFMAs); per-wave iteration chains halve.
//      Double-buffered 64-key staging, XCD pinning ((b,kvh)=bid&7), paired
//      q-tiles {31-p,p} (33 identical iterations), exp2 softmax + defer-max,
//      setprio. 4-way split-K merge at tile end via LDS scratch.
//   7. out = ao @ woT (fp32 out)
// ---------------------------------------------------------------------------

using bf16 = __bf16;
using bf16x4 = __attribute__((ext_vector_type(4))) __bf16;
using bf16x8 = __attribute__((ext_vector_type(8))) __bf16;
using s16x4  = __attribute__((ext_vector_type(4))) short;
using f32x4  = __attribute__((ext_vector_type(4))) float;

#define SEQ 2048
#define NH 16
#define NKVH 4
#define HD 128

// finite "minus infinity": combine algebra maps fully-masked groups to
// weight exp2((NEG-m*)*scl2) == 0, annihilating their garbage l/oT (R6-proven)
#define NEG (-3.0e38f)

// 16x16x16 bf16 MFMA (K=16) — C layout of a prior 16x16 MFMA feeds B directly.
#if defined(__has_builtin)
#if __has_builtin(__builtin_amdgcn_mfma_f32_16x16x16bf16_1k)
#define HAVE_1K 1
#endif
#endif
__device__ __forceinline__ f32x4 mfma_16x16x16(bf16x4 a, bf16x4 b, f32x4 c) {
#ifdef HAVE_1K
    return __builtin_amdgcn_mfma_f32_16x16x16bf16_1k(
        __builtin_bit_cast(s16x4, a), __builtin_bit_cast(s16x4, b), c, 0, 0, 0);
#else
    f32x4 d;
    asm volatile("v_mfma_f32_16x16x16_bf16 %0, %1, %2, %3"
                 : "=v"(d) : "v"(a), "v"(b), "v"(c));
    return d;
#endif
}

// native exp2 (v_exp_f32)
__device__ __forceinline__ float fast_exp2(float x) {
#if defined(__has_builtin)
#if __has_builtin(__builtin_amdgcn_exp2f)
    return __builtin_amdgcn_exp2f(x);
#else
    return exp2f(x);
#endif
#else
    return exp2f(x);
#endif
}

// async global->LDS, 16B per lane. LDS dest must be wave-uniform base + lane*16.
__device__ __forceinline__ void load_lds16(const bf16* g, bf16* l) {
    __builtin_amdgcn_global_load_lds(
        (const __attribute__((address_space(1))) unsigned int*)g,
        (__attribute__((address_space(3))) unsigned int*)l, 16, 0, 0);
}

// ---------------------------------------------------------------------------
__global__ __launch_bounds__(256) void cvt_f32_bf16(const float* __restrict__ in,
                                                    bf16* __restrict__ out, int n8) {
    int i = blockIdx.x * 256 + threadIdx.x;
    if (i >= n8) return;
    const float4* p = (const float4*)in + (long)i * 2;
    float4 f0 = p[0], f1 = p[1];
    bf16x8 o = {(bf16)f0.x, (bf16)f0.y, (bf16)f0.z, (bf16)f0.w,
                (bf16)f1.x, (bf16)f1.y, (bf16)f1.z, (bf16)f1.w};
    *((bf16x8*)out + i) = o;
}

// 2D transpose + cast: in fp32 [R][C] -> out bf16 [C][R]
__global__ void transpose2d(const float* __restrict__ in, bf16* __restrict__ out,
                            int R, int C) {
    __shared__ bf16 tile[32][33];
    int x  = blockIdx.x * 32 + threadIdx.x;
    int y0 = blockIdx.y * 32 + threadIdx.y;
#pragma unroll
    for (int i = 0; i < 32; i += 8) {
        int y = y0 + i;
        if (y < R && x < C) tile[threadIdx.y + i][threadIdx.x] = (bf16)in[(long)y * C + x];
    }
    __syncthreads();
    int ox  = blockIdx.y * 32 + threadIdx.x;
    int oy0 = blockIdx.x * 32 + threadIdx.y;
#pragma unroll
    for (int i = 0; i < 32; i += 8) {
        int oy = oy0 + i;
        if (oy < C && ox < R) out[(long)oy * R + ox] = tile[threadIdx.x][threadIdx.y + i];
    }
}

// ---------------------------------------------------------------------------
// GEMM: C[M][N] = A[M][K] @ BT[N][K]^T, bf16 in, fp32 acc, CT out.
// m97 recipe: 128x128 tile, BK=32, global_load_lds width-16 staging.
template <typename CT>
__global__ __launch_bounds__(256) void gemm_bt(const bf16* __restrict__ A,
                                               const bf16* __restrict__ BT,
                                               CT* __restrict__ C,
                                               int M, int N, int K) {
    __shared__ bf16 As[128][32];
    __shared__ bf16 Bs[128][32];
    const int tid  = threadIdx.x;
    const int wave = tid >> 6, lane = tid & 63;
    const int m0 = blockIdx.y * 128, n0 = blockIdx.x * 128;
    const int wm = (wave >> 1) * 64, wn = (wave & 1) * 64;
    const int lrow = lane & 15, quad = lane >> 4;
    const int lko = quad * 8;

    const bf16* ga0 = A  + (long)(m0 + (tid >> 2)) * K + (tid & 3) * 8;
    const bf16* ga1 = ga0 + 64L * K;
    const bf16* gb0 = BT + (long)(n0 + (tid >> 2)) * K + (tid & 3) * 8;
    const bf16* gb1 = gb0 + 64L * K;
    bf16* la0 = &As[0][0] + tid * 8;
    bf16* la1 = la0 + 2048;
    bf16* lb0 = &Bs[0][0] + tid * 8;
    bf16* lb1 = lb0 + 2048;

    f32x4 acc[4][4] = {};

    for (int k0 = 0; k0 < K; k0 += 32) {
        load_lds16(ga0 + k0, la0);
        load_lds16(ga1 + k0, la1);
        load_lds16(gb0 + k0, lb0);
        load_lds16(gb1 + k0, lb1);
        __syncthreads();
        bf16x8 af[4], bfr[4];
#pragma unroll
        for (int i = 0; i < 4; ++i) af[i]  = *(const bf16x8*)(&As[wm + i * 16 + lrow][lko]);
#pragma unroll
        for (int j = 0; j < 4; ++j) bfr[j] = *(const bf16x8*)(&Bs[wn + j * 16 + lrow][lko]);
#pragma unroll
        for (int i = 0; i < 4; ++i)
#pragma unroll
            for (int j = 0; j < 4; ++j)
                acc[i][j] = __builtin_amdgcn_mfma_f32_16x16x32_bf16(af[i], bfr[j], acc[i][j], 0, 0, 0);
        __syncthreads();
    }
#pragma unroll
    for (int i = 0; i < 4; ++i) {
        int mrow0 = m0 + wm + i * 16 + quad * 4;
#pragma unroll
        for (int j = 0; j < 4; ++j) {
            int ncol = n0 + wn + j * 16 + lrow;
#pragma unroll
            for (int r = 0; r < 4; ++r)
                C[(long)(mrow0 + r) * N + ncol] = (CT)acc[i][j][r];
        }
    }
}

// ---------------------------------------------------------------------------
// Per-head RMSNorm, wave per 128-vector, in-place.
__global__ __launch_bounds__(256) void rmsnorm_head(bf16* __restrict__ X,
                                                    const float* __restrict__ W,
                                                    int nvec, int lhpr, int stride) {
    int v = blockIdx.x * 4 + (threadIdx.x >> 6);
    int lane = threadIdx.x & 63;
    if (v >= nvec) return;
    int row = v >> lhpr, head = v & ((1 << lhpr) - 1);
    bf16* x = X + (long)row * stride + head * HD;
    float fa = (float)x[lane * 2], fb = (float)x[lane * 2 + 1];
    float ss = fa * fa + fb * fb;
#pragma unroll
    for (int off = 1; off < 64; off <<= 1) ss += __shfl_xor(ss, off, 64);
    float r = rsqrtf(ss * (1.0f / 128.0f) + 1e-5f);
    x[lane * 2]     = (bf16)(fa * r * W[lane * 2]);
    x[lane * 2 + 1] = (bf16)(fb * r * W[lane * 2 + 1]);
}

// ---------------------------------------------------------------------------
// Repack K (post-RMSNorm) into fragment-major tiles:
// kf[(b*4+kvh)*32 + kt][nt(4)][ks(4)][lane(64)][8] with
//   key = kt*64 + nt*16 + (lane&15), d = ks*32 + (lane>>4)*8 + j.
__global__ __launch_bounds__(256) void repack_k(const bf16* __restrict__ xkv,
                                                bf16* __restrict__ kf) {
    int kt = blockIdx.x, kvh = blockIdx.y, b = blockIdx.z;
    int tid = threadIdx.x, lane = tid & 63, ks = tid >> 6;
    int lrow = lane & 15, quad = lane >> 4;
    const bf16* src = xkv + ((long)b * SEQ + kt * 64) * 1024 + kvh * HD;
    bf16* dst = kf + ((long)((b * NKVH + kvh) * 32 + kt)) * 8192;
#pragma unroll
    for (int nt = 0; nt < 4; ++nt) {
        bf16x8 v = *(const bf16x8*)(src + (long)(nt * 16 + lrow) * 1024 + ks * 32 + quad * 8);
        *(bf16x8*)(dst + ((nt * 4 + ks) * 64 + lane) * 8) = v;
    }
}

// Repack V^T into fragment-major tiles:
// vf[(b*4+kvh)*32 + kt][nt(4)][dt(8)][lane(64)][4] with
//   d = dt*16 + (lane&15), key = kt*64 + nt*16 + (lane>>4)*4 + j.
__global__ __launch_bounds__(256) void repack_v(const bf16* __restrict__ xkv,
                                                bf16* __restrict__ vf) {
    __shared__ bf16 Vls[64][136];
    int kt = blockIdx.x, kvh = blockIdx.y, b = blockIdx.z;
    int tid = threadIdx.x;
    const bf16* src = xkv + ((long)b * SEQ + kt * 64) * 1024 + 512 + kvh * HD;
#pragma unroll
    for (int p = 0; p < 4; ++p) {
        int c = p * 256 + tid;
        int r = c >> 4, dc = (c & 15) * 8;
        *(uint4*)(&Vls[r][dc]) = *(const uint4*)(src + (long)r * 1024 + dc);
    }
    __syncthreads();
    int lane = tid & 63, w = tid >> 6, lrow = lane & 15, quad = lane >> 4;
    bf16* dst = vf + ((long)((b * NKVH + kvh) * 32 + kt)) * 8192;
#pragma unroll
    for (int nt = 0; nt < 4; ++nt)
#pragma unroll
        for (int dtl = 0; dtl < 2; ++dtl) {
            int dt = w * 2 + dtl;
            bf16x4 v = {Vls[nt * 16 + quad * 4 + 0][dt * 16 + lrow],
                        Vls[nt * 16 + quad * 4 + 1][dt * 16 + lrow],
                        Vls[nt * 16 + quad * 4 + 2][dt * 16 + lrow],
                        Vls[nt * 16 + quad * 4 + 3][dt * 16 + lrow]};
            *(bf16x4*)(dst + ((nt * 8 + dt) * 64 + lane) * 4) = v;
        }
}

// ---------------------------------------------------------------------------
// Flash attention: 512 threads, 8 waves = 2 q-halves (w2) x 4 key-quarters
// (grpW), 2 Q-fragments per wave (32 q-rows). Per staged 64-key pair, wave
// handles its 16-key quarter for its 32 q-rows: every K/V LDS read feeds 2
// MFMAs (R7 reuse), at R6's 16 waves/CU occupancy; per-iteration dependent
// chains halve vs R6. 4-way split-K merge at tile end (NEG-sentinel algebra
// zeroes masked groups: a_g = exp2((NEG-m*)*scl2) == 0).
// Grid 512; XCD pinning (b,kvh)=bid&7; paired q-tiles {31-p,p} -> 33
// identical iterations per block under any placement.
__global__ __launch_bounds__(512, 4) void attn_kernel(const bf16* __restrict__ Q,
                                                      const bf16* __restrict__ KF,
                                                      const bf16* __restrict__ VF,
                                                      bf16* __restrict__ O) {
    // [K buf0 | K buf1 | V buf0 | V buf1], 16 KB each = 64 KB; whole array
    // doubles as f32 scratch (16384 floats) for the split-K combine.
    __shared__ bf16 SMEM[32768];
    const int tid = threadIdx.x, wave = tid >> 6, lane = tid & 63;
    const int w2 = wave & 1, grpW = wave >> 1;   // q-half, key-quarter
    const int bid = blockIdx.x;
    const int grp = bid & 7;                  // -> XCD via bid%8 round-robin
    const int b = grp >> 2, kvh = grp & 3;
    const int slot = bid >> 3;                // 0..63
    const int pr = slot & 15;
    const int h = kvh * 4 + (slot >> 4);
    const int lrow = lane & 15, quad = lane >> 4;
    const float scl2 = 0.12751744f;     // (1/sqrt(128)) * log2(e)
    const float THR = 62.7f;            // ~8 ln-units in raw-score domain

    const int qt1 = 31 - pr, qt2 = pr;

    const bf16* kfb = KF + ((long)(b * NKVH + kvh) * 32) * 8192;
    const bf16* vfb = VF + ((long)(b * NKVH + kvh) * 32) * 8192;

    // stage 64-key pair into buffer bsel: 512 thr x 4 x 16B (K 16KB + V 16KB)
    auto stage = [&](int pair, int bsel) {
        const bf16* kg = kfb + (long)pair * 8192 + tid * 8;
        const bf16* vg = vfb + (long)pair * 8192 + tid * 8;
        bf16* kd = SMEM + bsel * 8192 + tid * 8;
        bf16* vd = SMEM + 16384 + bsel * 8192 + tid * 8;
        load_lds16(kg, kd);
        load_lds16(kg + 4096, kd + 4096);
        load_lds16(vg, vd);
        load_lds16(vg + 4096, vd + 4096);
    };

    float m_i[2] = {NEG, NEG}, l_i[2] = {0.f, 0.f};
    f32x4 oT[2][8] = {};   // [frag][dt]: d = dt*16 + quad*4 + r, q = lane&15
    bf16x8 bq[2][4];       // [frag][ks]

    // 4-way split-K combine (groups 1..3 -> group 0) + output write + reset.
    // Phase1: dt0-3 + (m,l); progressive online merge tracks per-group factor
    // c[f][g-1] for the dt4-7 contributions merged in phase2.
    auto combine_write_reset = [&](int qt) {
        float c[2][3];
        float* vs = (float*)SMEM;
        const int entry = ((grpW - 1) * 2 + w2) * 64 + lane;   // grpW>=1
        __syncthreads();
        if (grpW >= 1) {
#pragma unroll
            for (int f = 0; f < 2; ++f) {
                float* d = vs + (entry * 2 + f) * 18;
#pragma unroll
                for (int dt = 0; dt < 4; ++dt)
#pragma unroll
                    for (int r = 0; r < 4; ++r) d[dt * 4 + r] = oT[f][dt][r];
                d[16] = m_i[f]; d[17] = l_i[f];
            }
        }
        __syncthreads();
        if (grpW == 0) {
#pragma unroll
            for (int f = 0; f < 2; ++f) {
#pragma unroll
                for (int g = 1; g <= 3; ++g) {
                    const float* s = vs + ((((g - 1) * 2 + w2) * 64 + lane) * 2 + f) * 18;
                    float m1 = s[16], l1 = s[17];
                    float ms = fmaxf(m_i[f], m1);
                    float a0 = fast_exp2((m_i[f] - ms) * scl2);
                    float a1 = fast_exp2((m1 - ms) * scl2);
                    l_i[f] = a0 * l_i[f] + a1 * l1;
#pragma unroll
                    for (int dt = 0; dt < 4; ++dt)
#pragma unroll
                        for (int r = 0; r < 4; ++r)
                            oT[f][dt][r] = a0 * oT[f][dt][r] + a1 * s[dt * 4 + r];
#pragma unroll
                    for (int dt = 4; dt < 8; ++dt)
#pragma unroll
                        for (int r = 0; r < 4; ++r) oT[f][dt][r] *= a0;
#pragma unroll
                    for (int j = 1; j < g; ++j) c[f][j - 1] *= a0;
                    c[f][g - 1] = a1;
                    m_i[f] = ms;
                }
            }
        }
        __syncthreads();
        if (grpW >= 1) {
#pragma unroll
            for (int f = 0; f < 2; ++f) {
                float* d = vs + (entry * 2 + f) * 16;
#pragma unroll
                for (int dt = 4; dt < 8; ++dt)
#pragma unroll
                    for (int r = 0; r < 4; ++r) d[(dt - 4) * 4 + r] = oT[f][dt][r];
            }
        }
        __syncthreads();
        if (grpW == 0) {
#pragma unroll
            for (int f = 0; f < 2; ++f) {
#pragma unroll
                for (int g = 1; g <= 3; ++g) {
                    const float* s = vs + ((((g - 1) * 2 + w2) * 64 + lane) * 2 + f) * 16;
#pragma unroll
                    for (int dt = 4; dt < 8; ++dt)
#pragma unroll
                        for (int r = 0; r < 4; ++r)
                            oT[f][dt][r] += c[f][g - 1] * s[(dt - 4) * 4 + r];
                }
                float inv_l = 1.0f / l_i[f];
                int qrow = qt * 64 + w2 * 32 + f * 16 + lrow;
                bf16* obase = O + ((long)(b * SEQ + qrow)) * (NH * HD) + h * HD;
#pragma unroll
                for (int dt = 0; dt < 8; ++dt) {
                    bf16x4 o = {(bf16)(oT[f][dt][0] * inv_l), (bf16)(oT[f][dt][1] * inv_l),
                                (bf16)(oT[f][dt][2] * inv_l), (bf16)(oT[f][dt][3] * inv_l)};
                    *(bf16x4*)(obase + dt * 16 + quad * 4) = o;
                }
            }
        }
        __syncthreads();   // scratch/LDS free for restage
#pragma unroll
        for (int f = 0; f < 2; ++f) {
            m_i[f] = NEG; l_i[f] = 0.f;
#pragma unroll
            for (int dt = 0; dt < 8; ++dt)
#pragma unroll
                for (int r = 0; r < 4; ++r) oT[f][dt][r] = 0.f;
        }
    };

    // process staged pair i: this wave's 16-key quarter, both q-fragments
    auto process = [&](int i, int itN, int myqA, int cur) {
        const bool diag = (i == itN - 1);
        const bf16* kbase = SMEM + cur * 8192 + grpW * 2048;
        const bf16* vbase = SMEM + 16384 + cur * 8192 + grpW * 2048;
        const int myq[2] = {myqA, myqA + 16};

        f32x4 st[2];
        __builtin_amdgcn_s_setprio(1);
        {
            f32x4 a0 = {}, a1 = {};
#pragma unroll
            for (int ks = 0; ks < 4; ++ks) {
                bf16x8 ak = *(const bf16x8*)(kbase + ks * 512 + lane * 8);
                a0 = __builtin_amdgcn_mfma_f32_16x16x32_bf16(ak, bq[0][ks], a0, 0, 0, 0);
                a1 = __builtin_amdgcn_mfma_f32_16x16x32_bf16(ak, bq[1][ks], a1, 0, 0, 0);
            }
            st[0] = a0; st[1] = a1;
        }
        __builtin_amdgcn_s_setprio(0);
        if (diag) {
            const int kp0 = i * 64 + grpW * 16 + quad * 4;
#pragma unroll
            for (int f = 0; f < 2; ++f)
#pragma unroll
                for (int r = 0; r < 4; ++r)
                    if (kp0 + r > myq[f]) st[f][r] = NEG;
        }

        bf16x4 pf[2];
#pragma unroll
        for (int f = 0; f < 2; ++f) {
            float mx = fmaxf(fmaxf(st[f][0], st[f][1]), fmaxf(st[f][2], st[f][3]));
            mx = fmaxf(mx, __shfl_xor(mx, 16, 64));
            mx = fmaxf(mx, __shfl_xor(mx, 32, 64));

            if (!__all(mx - m_i[f] <= THR)) {
                float mnew = fmaxf(m_i[f], mx);
                float alpha = fast_exp2((m_i[f] - mnew) * scl2);
                l_i[f] *= alpha;
#pragma unroll
                for (int dt = 0; dt < 8; ++dt)
#pragma unroll
                    for (int r = 0; r < 4; ++r) oT[f][dt][r] *= alpha;
                m_i[f] = mnew;
            }
            float rs = 0.f;
#pragma unroll
            for (int r = 0; r < 4; ++r) {
                float p = fast_exp2((st[f][r] - m_i[f]) * scl2);
                st[f][r] = p;
                rs += p;
            }
            rs += __shfl_xor(rs, 16, 64);
            rs += __shfl_xor(rs, 32, 64);
            l_i[f] += rs;
            bf16x4 tt = {(bf16)st[f][0], (bf16)st[f][1],
                         (bf16)st[f][2], (bf16)st[f][3]};
            pf[f] = tt;
        }

        // PV: one av read feeds both fragments' MFMAs
        __builtin_amdgcn_s_setprio(1);
#pragma unroll
        for (int dt = 0; dt < 8; ++dt) {
            bf16x4 av = *(const bf16x4*)(vbase + dt * 256 + lane * 4);
            oT[0][dt] = mfma_16x16x16(av, pf[0], oT[0][dt]);
            oT[1][dt] = mfma_16x16x16(av, pf[1], oT[1][dt]);
        }
        __builtin_amdgcn_s_setprio(0);
    };

    // load both fragments' Q for a tile
    auto load_q = [&](int qt) {
#pragma unroll
        for (int f = 0; f < 2; ++f) {
            const int qr = qt * 64 + w2 * 32 + f * 16 + lrow;
            const bf16* qrow = Q + ((long)(b * SEQ + qr)) * (NH * HD) + h * HD;
#pragma unroll
            for (int ks = 0; ks < 4; ++ks)
                bq[f][ks] = *(const bf16x8*)(qrow + ks * 32 + quad * 8);
        }
    };

    // ---- tile 1: qt1, it1 = qt1+1 staged pairs --------------------------
    const int it1 = qt1 + 1;
    load_q(qt1);
    const int myq1a = qt1 * 64 + w2 * 32 + lrow;
    stage(0, 0);
    __syncthreads();
#pragma unroll 1
    for (int i = 0; i < it1; ++i) {
        const int cur = i & 1;
        if (i + 1 < it1) stage(i + 1, cur ^ 1);   // seam: no prefetch (combine scribbles SMEM)
        process(i, it1, myq1a, cur);
        __syncthreads();
    }
    combine_write_reset(qt1);

    // ---- tile 2: qt2, it2 = qt2+1 staged pairs --------------------------
    const int it2 = qt2 + 1;
    load_q(qt2);
    const int myq2a = qt2 * 64 + w2 * 32 + lrow;
    stage(0, 0);
    __syncthreads();
#pragma unroll 1
    for (int i = 0; i < it2; ++i) {
        const int cur = i & 1;
        if (i + 1 < it2) stage(i + 1, cur ^ 1);
        process(i, it2, myq2a, cur);
        __syncthreads();
    }
    combine_write_reset(qt2);
}

// ---------------------------------------------------------------------------
extern "C" void kernel_launch(void* const* d_in, const int* in_sizes, int n_in,
                              void* d_out, int out_size, void* d_ws, size_t ws_size,
                              hipStream_t stream) {
    const float* q_stream  = (const float*)d_in[0];
    const float* kv_stream = (const float*)d_in[1];
    const float* wq  = (const float*)d_in[2];
    const float* wk  = (const float*)d_in[3];
    const float* wv  = (const float*)d_in[4];
    const float* wo  = (const float*)d_in[5];
    const float* qnw = (const float*)d_in[6];
    const float* knw = (const float*)d_in[7];
    float* out = (float*)d_out;

    // workspace (bf16 elems), total 30M elems = 60MB
    bf16* ws   = (bf16*)d_ws;
    bf16* sb   = ws;                        // 8M: stream buf, later attn out
    bf16* wqT  = ws + 8L * 1024 * 1024;     // 4M: wq^T, later wo^T
    bf16* wkvT = wqT + 4L * 1024 * 1024;    // 2M: [wk^T ; wv^T] = [1024][2048]
    bf16* xq   = wkvT + 2L * 1024 * 1024;   // 8M: [4096][2048]
    bf16* xkv  = xq + 8L * 1024 * 1024;     // 4M: [4096][1024] = [K | V]
    bf16* kf   = xkv + 4L * 1024 * 1024;    // 2M: K fragment-major
    bf16* vf   = kf + 2L * 1024 * 1024;     // 2M: V^T fragment-major

    dim3 tb(32, 8);
    cvt_f32_bf16<<<4096, 256, 0, stream>>>(q_stream, sb, 1048576);
    transpose2d<<<dim3(64, 64), tb, 0, stream>>>(wq, wqT, 2048, 2048);
    transpose2d<<<dim3(16, 64), tb, 0, stream>>>(wk, wkvT, 2048, 512);
    transpose2d<<<dim3(16, 64), tb, 0, stream>>>(wv, wkvT + 512L * 2048, 2048, 512);
    gemm_bt<bf16><<<dim3(16, 32), 256, 0, stream>>>(sb, wqT, xq, 4096, 2048, 2048);
    cvt_f32_bf16<<<4096, 256, 0, stream>>>(kv_stream, sb, 1048576);
    transpose2d<<<dim3(64, 64), tb, 0, stream>>>(wo, wqT, 2048, 2048);
    gemm_bt<bf16><<<dim3(8, 32), 256, 0, stream>>>(sb, wkvT, xkv, 4096, 1024, 2048);
    rmsnorm_head<<<(4096 * 16) / 4, 256, 0, stream>>>(xq, qnw, 4096 * 16, 4, 2048);
    rmsnorm_head<<<(4096 * 4) / 4, 256, 0, stream>>>(xkv, knw, 4096 * 4, 2, 1024);
    repack_k<<<dim3(32, 4, 2), 256, 0, stream>>>(xkv, kf);
    repack_v<<<dim3(32, 4, 2), 256, 0, stream>>>(xkv, vf);
    attn_kernel<<<dim3(512), dim3(512), 0, stream>>>(xq, kf, vf, sb);
    gemm_bt<float><<<dim3(16, 32), 256, 0, stream>>>(sb, wqT, out, 4096, 2048, 2048);

    (void)in_sizes; (void)n_in; (void)out_size; (void)ws_size;
}

// Round 9
// 384.916 us; speedup vs baseline: 1.1037x; 1.1037x over previous
//
#include <hip/hip_runtime.h>
#include <cstdint>

// ---------------------------------------------------------------------------
// JanusCrossAttention: B=2,S=2048, Q_DIM=KV_DIM=2048, H=16, D=128, KVH=4
// I/O fp32; internals bf16 MFMA, fp32 accumulate.
//   1. cvt q_stream -> bf16 sb ; transpose weights -> bf16 [N][K]
//   2. xq = sb @ wqT  (double-buffered global_load_lds GEMM, XCD-swizzled)
//   3. cvt kv_stream -> sb ; xkv = sb @ wkvT  (fused K|V, N=1024)
//   4. per-head RMSNorm xq, xk
//   5. repack K and V^T into MFMA-fragment-major tiles
//   6. flash attention: R6 structure (best measured, 70.8 us): 512 threads,
//      8 waves = 4 q-subtiles x 2 key-parity groups, 2-way split-K merge,
//      double-buffered 64-key staging, XCD pinning ((b,kvh)=bid&7), paired
//      q-tiles {31-p,p} (33 identical iterations), exp2 softmax + defer-max.
//      R8 lesson: 2-frag variant spilled (launch_bounds cap 128 regs, demand
//      ~130 -> VGPR=64 + 24 MB scratch writes). Reverted.
//   7. out = ao @ woT (fp32 out)
// GEMMs dominate the pipeline (~270 of 404 us at ~400 TF effective): grids
// give only 1-2 blocks/CU, so m97's implicit 3-block overlap is absent and
// each K-step's staging drain is exposed. Fix: explicit LDS double-buffer
// (stage k+1 during compute k, one barrier/iter) + XCD block swizzle.
// ---------------------------------------------------------------------------

using bf16 = __bf16;
using bf16x4 = __attribute__((ext_vector_type(4))) __bf16;
using bf16x8 = __attribute__((ext_vector_type(8))) __bf16;
using s16x4  = __attribute__((ext_vector_type(4))) short;
using f32x4  = __attribute__((ext_vector_type(4))) float;

#define SEQ 2048
#define NH 16
#define NKVH 4
#define HD 128

// finite "minus infinity": avoids inf-inf NaNs in the split-K defer-max path
#define NEG (-3.0e38f)

// 16x16x16 bf16 MFMA (K=16) — C layout of a prior 16x16 MFMA feeds B directly.
#if defined(__has_builtin)
#if __has_builtin(__builtin_amdgcn_mfma_f32_16x16x16bf16_1k)
#define HAVE_1K 1
#endif
#endif
__device__ __forceinline__ f32x4 mfma_16x16x16(bf16x4 a, bf16x4 b, f32x4 c) {
#ifdef HAVE_1K
    return __builtin_amdgcn_mfma_f32_16x16x16bf16_1k(
        __builtin_bit_cast(s16x4, a), __builtin_bit_cast(s16x4, b), c, 0, 0, 0);
#else
    f32x4 d;
    asm volatile("v_mfma_f32_16x16x16_bf16 %0, %1, %2, %3"
                 : "=v"(d) : "v"(a), "v"(b), "v"(c));
    return d;
#endif
}

// native exp2 (v_exp_f32)
__device__ __forceinline__ float fast_exp2(float x) {
#if defined(__has_builtin)
#if __has_builtin(__builtin_amdgcn_exp2f)
    return __builtin_amdgcn_exp2f(x);
#else
    return exp2f(x);
#endif
#else
    return exp2f(x);
#endif
}

// async global->LDS, 16B per lane. LDS dest must be wave-uniform base + lane*16.
__device__ __forceinline__ void load_lds16(const bf16* g, bf16* l) {
    __builtin_amdgcn_global_load_lds(
        (const __attribute__((address_space(1))) unsigned int*)g,
        (__attribute__((address_space(3))) unsigned int*)l, 16, 0, 0);
}

// ---------------------------------------------------------------------------
__global__ __launch_bounds__(256) void cvt_f32_bf16(const float* __restrict__ in,
                                                    bf16* __restrict__ out, int n8) {
    int i = blockIdx.x * 256 + threadIdx.x;
    if (i >= n8) return;
    const float4* p = (const float4*)in + (long)i * 2;
    float4 f0 = p[0], f1 = p[1];
    bf16x8 o = {(bf16)f0.x, (bf16)f0.y, (bf16)f0.z, (bf16)f0.w,
                (bf16)f1.x, (bf16)f1.y, (bf16)f1.z, (bf16)f1.w};
    *((bf16x8*)out + i) = o;
}

// 2D transpose + cast: in fp32 [R][C] -> out bf16 [C][R]
__global__ void transpose2d(const float* __restrict__ in, bf16* __restrict__ out,
                            int R, int C) {
    __shared__ bf16 tile[32][33];
    int x  = blockIdx.x * 32 + threadIdx.x;
    int y0 = blockIdx.y * 32 + threadIdx.y;
#pragma unroll
    for (int i = 0; i < 32; i += 8) {
        int y = y0 + i;
        if (y < R && x < C) tile[threadIdx.y + i][threadIdx.x] = (bf16)in[(long)y * C + x];
    }
    __syncthreads();
    int ox  = blockIdx.y * 32 + threadIdx.x;
    int oy0 = blockIdx.x * 32 + threadIdx.y;
#pragma unroll
    for (int i = 0; i < 32; i += 8) {
        int oy = oy0 + i;
        if (oy < C && ox < R) out[(long)oy * R + ox] = tile[threadIdx.x][threadIdx.y + i];
    }
}

// ---------------------------------------------------------------------------
// GEMM: C[M][N] = A[M][K] @ BT[N][K]^T, bf16 in, fp32 acc, CT out.
// 128x128 tile, BK=32, global_load_lds width-16 staging, now DOUBLE-BUFFERED:
// stage K-tile it+1 while computing it, one barrier per iteration. At our
// grids (1-2 blocks/CU) there is no implicit cross-block overlap to hide the
// staging drain (m97's 3-block regime), so the explicit pipeline pays here.
// XCD swizzle: bid%8 -> XCD (R3-proven); give each XCD a contiguous tile
// chunk so A/B panels stay in its private L2. All call-site grids are %8==0.
template <typename CT>
__global__ __launch_bounds__(256) void gemm_bt(const bf16* __restrict__ A,
                                               const bf16* __restrict__ BT,
                                               CT* __restrict__ C,
                                               int M, int N, int K) {
    __shared__ bf16 As[2][128][32];
    __shared__ bf16 Bs[2][128][32];
    const int tid  = threadIdx.x;
    const int wave = tid >> 6, lane = tid & 63;
    const int nwg = gridDim.x * gridDim.y;
    const int bid = blockIdx.y * gridDim.x + blockIdx.x;
    const int swz = (bid & 7) * (nwg >> 3) + (bid >> 3);
    const int bx = swz % gridDim.x, by = swz / gridDim.x;
    const int m0 = by * 128, n0 = bx * 128;
    const int wm = (wave >> 1) * 64, wn = (wave & 1) * 64;
    const int lrow = lane & 15, quad = lane >> 4;
    const int lko = quad * 8;

    const bf16* ga0 = A  + (long)(m0 + (tid >> 2)) * K + (tid & 3) * 8;
    const bf16* ga1 = ga0 + 64L * K;
    const bf16* gb0 = BT + (long)(n0 + (tid >> 2)) * K + (tid & 3) * 8;
    const bf16* gb1 = gb0 + 64L * K;
    bf16* la0 = &As[0][0][0] + tid * 8;
    bf16* lb0 = &Bs[0][0][0] + tid * 8;

    f32x4 acc[4][4] = {};

    const int nIt = K >> 5;
    // prologue: stage k-tile 0 into buffer 0
    load_lds16(ga0, la0);
    load_lds16(ga1, la0 + 2048);
    load_lds16(gb0, lb0);
    load_lds16(gb1, lb0 + 2048);
    __syncthreads();

#pragma unroll 1
    for (int it = 0; it < nIt; ++it) {
        const int cur = it & 1;
        if (it + 1 < nIt) {
            const int k0 = (it + 1) * 32;
            bf16* la = la0 + (cur ^ 1) * 4096;
            bf16* lb = lb0 + (cur ^ 1) * 4096;
            load_lds16(ga0 + k0, la);
            load_lds16(ga1 + k0, la + 2048);
            load_lds16(gb0 + k0, lb);
            load_lds16(gb1 + k0, lb + 2048);
        }
        bf16x8 af[4], bfr[4];
#pragma unroll
        for (int i = 0; i < 4; ++i) af[i]  = *(const bf16x8*)(&As[cur][wm + i * 16 + lrow][lko]);
#pragma unroll
        for (int j = 0; j < 4; ++j) bfr[j] = *(const bf16x8*)(&Bs[cur][wn + j * 16 + lrow][lko]);
#pragma unroll
        for (int i = 0; i < 4; ++i)
#pragma unroll
            for (int j = 0; j < 4; ++j)
                acc[i][j] = __builtin_amdgcn_mfma_f32_16x16x32_bf16(af[i], bfr[j], acc[i][j], 0, 0, 0);
        __syncthreads();   // releases buffer cur for restage at it+1; drains staged loads
    }
#pragma unroll
    for (int i = 0; i < 4; ++i) {
        int mrow0 = m0 + wm + i * 16 + quad * 4;
#pragma unroll
        for (int j = 0; j < 4; ++j) {
            int ncol = n0 + wn + j * 16 + lrow;
#pragma unroll
            for (int r = 0; r < 4; ++r)
                C[(long)(mrow0 + r) * N + ncol] = (CT)acc[i][j][r];
        }
    }
}

// ---------------------------------------------------------------------------
// Per-head RMSNorm, wave per 128-vector, in-place.
__global__ __launch_bounds__(256) void rmsnorm_head(bf16* __restrict__ X,
                                                    const float* __restrict__ W,
                                                    int nvec, int lhpr, int stride) {
    int v = blockIdx.x * 4 + (threadIdx.x >> 6);
    int lane = threadIdx.x & 63;
    if (v >= nvec) return;
    int row = v >> lhpr, head = v & ((1 << lhpr) - 1);
    bf16* x = X + (long)row * stride + head * HD;
    float fa = (float)x[lane * 2], fb = (float)x[lane * 2 + 1];
    float ss = fa * fa + fb * fb;
#pragma unroll
    for (int off = 1; off < 64; off <<= 1) ss += __shfl_xor(ss, off, 64);
    float r = rsqrtf(ss * (1.0f / 128.0f) + 1e-5f);
    x[lane * 2]     = (bf16)(fa * r * W[lane * 2]);
    x[lane * 2 + 1] = (bf16)(fb * r * W[lane * 2 + 1]);
}

// ---------------------------------------------------------------------------
// Repack K (post-RMSNorm) into fragment-major tiles:
// kf[(b*4+kvh)*32 + kt][nt(4)][ks(4)][lane(64)][8] with
//   key = kt*64 + nt*16 + (lane&15), d = ks*32 + (lane>>4)*8 + j.
__global__ __launch_bounds__(256) void repack_k(const bf16* __restrict__ xkv,
                                                bf16* __restrict__ kf) {
    int kt = blockIdx.x, kvh = blockIdx.y, b = blockIdx.z;
    int tid = threadIdx.x, lane = tid & 63, ks = tid >> 6;
    int lrow = lane & 15, quad = lane >> 4;
    const bf16* src = xkv + ((long)b * SEQ + kt * 64) * 1024 + kvh * HD;
    bf16* dst = kf + ((long)((b * NKVH + kvh) * 32 + kt)) * 8192;
#pragma unroll
    for (int nt = 0; nt < 4; ++nt) {
        bf16x8 v = *(const bf16x8*)(src + (long)(nt * 16 + lrow) * 1024 + ks * 32 + quad * 8);
        *(bf16x8*)(dst + ((nt * 4 + ks) * 64 + lane) * 8) = v;
    }
}

// Repack V^T into fragment-major tiles:
// vf[(b*4+kvh)*32 + kt][nt(4)][dt(8)][lane(64)][4] with
//   d = dt*16 + (lane&15), key = kt*64 + nt*16 + (lane>>4)*4 + j.
__global__ __launch_bounds__(256) void repack_v(const bf16* __restrict__ xkv,
                                                bf16* __restrict__ vf) {
    __shared__ bf16 Vls[64][136];
    int kt = blockIdx.x, kvh = blockIdx.y, b = blockIdx.z;
    int tid = threadIdx.x;
    const bf16* src = xkv + ((long)b * SEQ + kt * 64) * 1024 + 512 + kvh * HD;
#pragma unroll
    for (int p = 0; p < 4; ++p) {
        int c = p * 256 + tid;
        int r = c >> 4, dc = (c & 15) * 8;
        *(uint4*)(&Vls[r][dc]) = *(const uint4*)(src + (long)r * 1024 + dc);
    }
    __syncthreads();
    int lane = tid & 63, w = tid >> 6, lrow = lane & 15, quad = lane >> 4;
    bf16* dst = vf + ((long)((b * NKVH + kvh) * 32 + kt)) * 8192;
#pragma unroll
    for (int nt = 0; nt < 4; ++nt)
#pragma unroll
        for (int dtl = 0; dtl < 2; ++dtl) {
            int dt = w * 2 + dtl;
            bf16x4 v = {Vls[nt * 16 + quad * 4 + 0][dt * 16 + lrow],
                        Vls[nt * 16 + quad * 4 + 1][dt * 16 + lrow],
                        Vls[nt * 16 + quad * 4 + 2][dt * 16 + lrow],
                        Vls[nt * 16 + quad * 4 + 3][dt * 16 + lrow]};
            *(bf16x4*)(dst + ((nt * 8 + dt) * 64 + lane) * 4) = v;
        }
}

// ---------------------------------------------------------------------------
// Flash attention: R6 structure verbatim (best measured: 70.8 us).
// 512-thread blocks, 8 waves = 4 q-subtiles (w4) x 2 key-parity groups
// (grpW); per 64-key staged pair both groups work every iteration; 2-way
// split-K merge at tile end via LDS scratch. Grid 512 -> 2 blocks/CU ->
// 16 waves/CU. XCD pinning: (b,kvh)=bid&7. Paired q-tiles {31-p,p}:
// 33 identical iterations per block under any placement.
__global__ __launch_bounds__(512, 4) void attn_kernel(const bf16* __restrict__ Q,
                                                      const bf16* __restrict__ KF,
                                                      const bf16* __restrict__ VF,
                                                      bf16* __restrict__ O) {
    __shared__ bf16 Kf[2][8192];   // [buf][half(2)·nt(2)·ks(4)·512] — 32 KB
    __shared__ bf16 Vf[2][8192];   // [buf][half(2)·nt(2)·dt(8)·256] — 32 KB
    const int tid = threadIdx.x, wave = tid >> 6, lane = tid & 63;
    const int w4 = wave & 3, grpW = wave >> 2;
    const int bid = blockIdx.x;
    const int grp = bid & 7;                  // -> XCD via bid%8 round-robin
    const int b = grp >> 2, kvh = grp & 3;
    const int slot = bid >> 3;                // 0..63
    const int pr = slot & 15;
    const int h = kvh * 4 + (slot >> 4);
    const int lrow = lane & 15, quad = lane >> 4;
    const float scl2 = 0.12751744f;     // (1/sqrt(128)) * log2(e)
    const float THR = 62.7f;            // ~8 ln-units in raw-score domain

    const int qt1 = 31 - pr, qt2 = pr;

    const bf16* kfb = KF + ((long)(b * NKVH + kvh) * 32) * 8192;
    const bf16* vfb = VF + ((long)(b * NKVH + kvh) * 32) * 8192;

    // stage 64-key pair (== repack tile) into buffer bsel: 512thr x 2x16B each
    auto stage = [&](int pair, int bsel) {
        const bf16* kg = kfb + (long)pair * 8192 + tid * 8;
        const bf16* vg = vfb + (long)pair * 8192 + tid * 8;
        bf16* kd = &Kf[bsel][0] + tid * 8;
        bf16* vd = &Vf[bsel][0] + tid * 8;
        load_lds16(kg, kd);
        load_lds16(kg + 4096, kd + 4096);
        load_lds16(vg, vd);
        load_lds16(vg + 4096, vd + 4096);
    };

    float m_i = NEG, l_i = 0.f;
    f32x4 oT[8] = {};   // out^T: d = dt*16 + quad*4 + r, q = lane&15
    bf16x8 bqw[4];

    // split-K combine (group1 -> group0 via Vf scratch) + output write + reset
    auto combine_write_reset = [&](int qrow) {
        float a1keep = 0.f;
        float* vs = (float*)&Vf[0][0];
        const int sl = w4 * 64 + lane;
        __syncthreads();
        if (grpW == 1) {
            float* d = vs + sl * 18;
#pragma unroll
            for (int dt = 0; dt < 4; ++dt)
#pragma unroll
                for (int r = 0; r < 4; ++r) d[dt * 4 + r] = oT[dt][r];
            d[16] = m_i; d[17] = l_i;
        }
        __syncthreads();
        if (grpW == 0) {
            const float* s = vs + sl * 18;
            float m1 = s[16], l1 = s[17];
            float ms = fmaxf(m_i, m1);
            float a0 = fast_exp2((m_i - ms) * scl2);
            float a1 = fast_exp2((m1 - ms) * scl2);
            a1keep = a1;
            l_i = a0 * l_i + a1 * l1;
#pragma unroll
            for (int dt = 0; dt < 4; ++dt)
#pragma unroll
                for (int r = 0; r < 4; ++r)
                    oT[dt][r] = a0 * oT[dt][r] + a1 * s[dt * 4 + r];
#pragma unroll
            for (int dt = 4; dt < 8; ++dt)
#pragma unroll
                for (int r = 0; r < 4; ++r) oT[dt][r] *= a0;
            m_i = ms;
        }
        __syncthreads();
        if (grpW == 1) {
            float* d = vs + sl * 16;
#pragma unroll
            for (int dt = 4; dt < 8; ++dt)
#pragma unroll
                for (int r = 0; r < 4; ++r) d[(dt - 4) * 4 + r] = oT[dt][r];
        }
        __syncthreads();
        if (grpW == 0) {
            const float* s = vs + sl * 16;
#pragma unroll
            for (int dt = 4; dt < 8; ++dt)
#pragma unroll
                for (int r = 0; r < 4; ++r) oT[dt][r] += a1keep * s[(dt - 4) * 4 + r];
            float inv_l = 1.0f / l_i;
            bf16* obase = O + ((long)(b * SEQ + qrow)) * (NH * HD) + h * HD;
#pragma unroll
            for (int dt = 0; dt < 8; ++dt) {
                bf16x4 o = {(bf16)(oT[dt][0] * inv_l), (bf16)(oT[dt][1] * inv_l),
                            (bf16)(oT[dt][2] * inv_l), (bf16)(oT[dt][3] * inv_l)};
                *(bf16x4*)(obase + dt * 16 + quad * 4) = o;
            }
        }
        __syncthreads();   // scratch/LDS free for restage
        m_i = NEG; l_i = 0.f;
#pragma unroll
        for (int dt = 0; dt < 8; ++dt)
#pragma unroll
            for (int r = 0; r < 4; ++r) oT[dt][r] = 0.f;
    };

    // process the current staged pair: group's 32-key block kbg
    auto process = [&](int i, int itN, int myq, int cur) {
        const int kbg = 2 * i + grpW;
        const bool diag = (i == itN - 1);
        const bf16* kbase = &Kf[cur][0] + grpW * 4096;
        const bf16* vbase = &Vf[cur][0] + grpW * 4096;

        f32x4 st[2];
        __builtin_amdgcn_s_setprio(1);
#pragma unroll
        for (int nt = 0; nt < 2; ++nt) {
            f32x4 acc = {};
#pragma unroll
            for (int ks = 0; ks < 4; ++ks) {
                bf16x8 ak = *(const bf16x8*)(kbase + (nt * 4 + ks) * 512 + lane * 8);
                acc = __builtin_amdgcn_mfma_f32_16x16x32_bf16(ak, bqw[ks], acc, 0, 0, 0);
            }
            st[nt] = acc;
        }
        __builtin_amdgcn_s_setprio(0);
        if (diag) {
#pragma unroll
            for (int nt = 0; nt < 2; ++nt) {
                int kp0 = kbg * 32 + nt * 16 + quad * 4;
#pragma unroll
                for (int r = 0; r < 4; ++r)
                    if (kp0 + r > myq) st[nt][r] = NEG;
            }
        }

        float mx = st[0][0];
#pragma unroll
        for (int nt = 0; nt < 2; ++nt)
#pragma unroll
            for (int r = 0; r < 4; ++r) mx = fmaxf(mx, st[nt][r]);
        mx = fmaxf(mx, __shfl_xor(mx, 16, 64));
        mx = fmaxf(mx, __shfl_xor(mx, 32, 64));

        if (!__all(mx - m_i <= THR)) {
            float mnew = fmaxf(m_i, mx);
            float alpha = fast_exp2((m_i - mnew) * scl2);
            l_i *= alpha;
#pragma unroll
            for (int dt = 0; dt < 8; ++dt)
#pragma unroll
                for (int r = 0; r < 4; ++r) oT[dt][r] *= alpha;
            m_i = mnew;
        }
        float rs = 0.f;
#pragma unroll
        for (int nt = 0; nt < 2; ++nt)
#pragma unroll
            for (int r = 0; r < 4; ++r) {
                float p = fast_exp2((st[nt][r] - m_i) * scl2);
                st[nt][r] = p;
                rs += p;
            }
        rs += __shfl_xor(rs, 16, 64);
        rs += __shfl_xor(rs, 32, 64);
        l_i += rs;

        bf16x4 pf[2];
#pragma unroll
        for (int nt = 0; nt < 2; ++nt) {
            bf16x4 tt = {(bf16)st[nt][0], (bf16)st[nt][1],
                         (bf16)st[nt][2], (bf16)st[nt][3]};
            pf[nt] = tt;
        }

        __builtin_amdgcn_s_setprio(1);
#pragma unroll
        for (int nt = 0; nt < 2; ++nt)
#pragma unroll
            for (int dt = 0; dt < 8; ++dt) {
                bf16x4 av = *(const bf16x4*)(vbase + (nt * 8 + dt) * 256 + lane * 4);
                oT[dt] = mfma_16x16x16(av, pf[nt], oT[dt]);
            }
        __builtin_amdgcn_s_setprio(0);
    };

    // ---- tile 1: qt1, it1 = qt1+1 staged pairs --------------------------
    const int it1 = qt1 + 1;
    const int myq1 = qt1 * 64 + w4 * 16 + lrow;
    {
        const bf16* qrow = Q + ((long)(b * SEQ + myq1)) * (NH * HD) + h * HD;
#pragma unroll
        for (int ks = 0; ks < 4; ++ks)
            bqw[ks] = *(const bf16x8*)(qrow + ks * 32 + quad * 8);
    }
    stage(0, 0);
    __syncthreads();
#pragma unroll 1
    for (int i = 0; i < it1; ++i) {
        const int cur = i & 1;
        if (i + 1 < it1) stage(i + 1, cur ^ 1);
        process(i, it1, myq1, cur);
        __syncthreads();
    }
    combine_write_reset(myq1);

    // ---- tile 2: qt2, it2 = qt2+1 staged pairs --------------------------
    const int it2 = qt2 + 1;
    const int myq2 = qt2 * 64 + w4 * 16 + lrow;
    {
        const bf16* qrow = Q + ((long)(b * SEQ + myq2)) * (NH * HD) + h * HD;
#pragma unroll
        for (int ks = 0; ks < 4; ++ks)
            bqw[ks] = *(const bf16x8*)(qrow + ks * 32 + quad * 8);
    }
    stage(0, 0);
    __syncthreads();
#pragma unroll 1
    for (int i = 0; i < it2; ++i) {
        const int cur = i & 1;
        if (i + 1 < it2) stage(i + 1, cur ^ 1);
        process(i, it2, myq2, cur);
        __syncthreads();
    }
    combine_write_reset(qt2 * 64 + w4 * 16 + lrow);
}

// ---------------------------------------------------------------------------
extern "C" void kernel_launch(void* const* d_in, const int* in_sizes, int n_in,
                              void* d_out, int out_size, void* d_ws, size_t ws_size,
                              hipStream_t stream) {
    const float* q_stream  = (const float*)d_in[0];
    const float* kv_stream = (const float*)d_in[1];
    const float* wq  = (const float*)d_in[2];
    const float* wk  = (const float*)d_in[3];
    const float* wv  = (const float*)d_in[4];
    const float* wo  = (const float*)d_in[5];
    const float* qnw = (const float*)d_in[6];
    const float* knw = (const float*)d_in[7];
    float* out = (float*)d_out;

    // workspace (bf16 elems), total 30M elems = 60MB
    bf16* ws   = (bf16*)d_ws;
    bf16* sb   = ws;                        // 8M: stream buf, later attn out
    bf16* wqT  = ws + 8L * 1024 * 1024;     // 4M: wq^T, later wo^T
    bf16* wkvT = wqT + 4L * 1024 * 1024;    // 2M: [wk^T ; wv^T] = [1024][2048]
    bf16* xq   = wkvT + 2L * 1024 * 1024;   // 8M: [4096][2048]
    bf16* xkv  = xq + 8L * 1024 * 1024;     // 4M: [4096][1024] = [K | V]
    bf16* kf   = xkv + 4L * 1024 * 1024;    // 2M: K fragment-major
    bf16* vf   = kf + 2L * 1024 * 1024;     // 2M: V^T fragment-major

    dim3 tb(32, 8);
    cvt_f32_bf16<<<4096, 256, 0, stream>>>(q_stream, sb, 1048576);
    transpose2d<<<dim3(64, 64), tb, 0, stream>>>(wq, wqT, 2048, 2048);
    transpose2d<<<dim3(16, 64), tb, 0, stream>>>(wk, wkvT, 2048, 512);
    transpose2d<<<dim3(16, 64), tb, 0, stream>>>(wv, wkvT + 512L * 2048, 2048, 512);
    gemm_bt<bf16><<<dim3(16, 32), 256, 0, stream>>>(sb, wqT, xq, 4096, 2048, 2048);
    cvt_f32_bf16<<<4096, 256, 0, stream>>>(kv_stream, sb, 1048576);
    transpose2d<<<dim3(64, 64), tb, 0, stream>>>(wo, wqT, 2048, 2048);
    gemm_bt<bf16><<<dim3(8, 32), 256, 0, stream>>>(sb, wkvT, xkv, 4096, 1024, 2048);
    rmsnorm_head<<<(4096 * 16) / 4, 256, 0, stream>>>(xq, qnw, 4096 * 16, 4, 2048);
    rmsnorm_head<<<(4096 * 4) / 4, 256, 0, stream>>>(xkv, knw, 4096 * 4, 2, 1024);
    repack_k<<<dim3(32, 4, 2), 256, 0, stream>>>(xkv, kf);
    repack_v<<<dim3(32, 4, 2), 256, 0, stream>>>(xkv, vf);
    attn_kernel<<<dim3(512), dim3(512), 0, stream>>>(xq, kf, vf, sb);
    gemm_bt<float><<<dim3(16, 32), 256, 0, stream>>>(sb, wqT, out, 4096, 2048, 2048);

    (void)in_sizes; (void)n_in; (void)out_size; (void)ws_size;
}